// Round 1
// baseline (127.529 us; speedup 1.0000x reference)
//
#include <hip/hip_runtime.h>

typedef short bf16x8 __attribute__((ext_vector_type(8)));   // 8 bf16 in 4 VGPRs
typedef float f32x4v __attribute__((ext_vector_type(4)));

// ---- constants derived from the reference ----
// grid = linspace(-1,1,12); centers c_k = -1 + (3+k)*2/11, k=0..7
// h = 0.4 + 1e-6 ; z_k = (x - c_k)/h = u - k*DLT,  u = (x - c0)/h
// basis_k = exp(-z_k^2/2) = exp2(A2*u^2) * exp2(B2*u)^k * exp2(GCF*k^2)
// The exp2(GCF*k^2) factor is constant per k and folded into the weights.
constexpr double H_D    = 0.4 + 1e-6;
constexpr double INVH_D = 1.0 / H_D;
constexpr double C0_D   = -1.0 + 6.0 / 11.0;
constexpr double DLT_D  = (2.0 / 11.0) / H_D;
constexpr double L2E_D  = 1.4426950408889634;

constexpr float INVH = (float)INVH_D;
constexpr float NC0H = (float)(-C0_D * INVH_D);           // u = x*INVH + NC0H
constexpr float A2f  = (float)(-0.5 * L2E_D);             // E0 = exp2(A2*u*u)
constexpr float B2f  = (float)(DLT_D * L2E_D);            // r  = exp2(B2*u)
constexpr float GCF  = (float)(-0.5 * DLT_D * DLT_D * L2E_D); // g_k = exp2(GCF*k*k)
constexpr float NL2E = (float)(-L2E_D);

__device__ __forceinline__ float fexp2(float v) {
#if __has_builtin(__builtin_amdgcn_exp2f)
  return __builtin_amdgcn_exp2f(v);
#else
  return exp2f(v);
#endif
}
__device__ __forceinline__ float frcp(float v) {
#if __has_builtin(__builtin_amdgcn_rcpf)
  return __builtin_amdgcn_rcpf(v);
#else
  return 1.0f / v;
#endif
}
__device__ __forceinline__ float siluf(float v) {
  // v * sigmoid(v) = v / (1 + 2^(-log2e * v))
  return v * frcp(1.0f + fexp2(NL2E * v));
}
// pack two fp32 -> one dword of two bf16 (round-half-up), via v_perm_b32
__device__ __forceinline__ unsigned pk2(float lo, float hi) {
  unsigned a = __float_as_uint(hi) + 0x8000u;
  unsigned b = __float_as_uint(lo) + 0x8000u;
  return __builtin_amdgcn_perm(a, b, 0x07060302u); // [a.hi16 : b.hi16]
}
__device__ __forceinline__ bf16x8 packfrag(const float (&v)[8]) {
  uint4 d;
  d.x = pk2(v[0], v[1]);
  d.y = pk2(v[2], v[3]);
  d.z = pk2(v[4], v[5]);
  d.w = pk2(v[6], v[7]);
  return __builtin_bit_cast(bf16x8, d);
}
// RNE fp32 -> bf16 (prep path, cost-free)
__device__ __forceinline__ unsigned rne16(float f) {
  unsigned u = __float_as_uint(f);
  return (u + 0x7fffu + ((u >> 16) & 1u)) >> 16;
}

// ---------------- prep: build fragment-ordered bf16 weights + bias ----------------
// K ordering: k = G*288 + t*32 + c   (G=0..3 channel-groups of 32, t=0..8 feature,
//                                     c = quad*8 + j channel within group)
// Fragment entry e = (G*9+t)*2 + h  (h = column half), lane l: col n = h*16 + (l&15),
// channels cbase = G*32 + (l>>4)*8 + (0..7)  -> matches MFMA B[k=quad*8+j][n=lane&15].
__global__ void kan_prep(const float* __restrict__ coeff,
                         const float* __restrict__ bw,
                         const float* __restrict__ bb,
                         const float* __restrict__ ew,
                         uint4* __restrict__ wfrag,
                         float* __restrict__ bias) {
  if (blockIdx.x == 18) {
    int n = threadIdx.x;
    if (n < 32) {
      float s = 0.f;
      for (int i = 0; i < 128; ++i) s += ew[i * 32 + n] * bb[i * 32 + n];
      bias[n] = s;
    }
    return;
  }
  const int e    = blockIdx.x * 4 + (threadIdx.x >> 6); // 0..71  (= s*2 + h)
  const int lane = threadIdx.x & 63;
  const int s = e >> 1, h = e & 1;
  const int G = s / 9, t = s % 9;
  const int n = h * 16 + (lane & 15);
  const int cbase = G * 32 + (lane >> 4) * 8;
  float v[8];
  if (t == 0) {
#pragma unroll
    for (int j = 0; j < 8; ++j) {
      int i = cbase + j;
      v[j] = ew[i * 32 + n] * bw[i * 32 + n];
    }
  } else {
    const int k = t - 1;
    const float g = exp2f(GCF * (float)(k * k)); // fold g_k into weight
#pragma unroll
    for (int j = 0; j < 8; ++j) {
      int i = cbase + j;
      v[j] = ew[i * 32 + n] * coeff[(i * 32 + n) * 8 + k] * g;
    }
  }
  uint4 d;
  d.x = (rne16(v[1]) << 16) | rne16(v[0]);
  d.y = (rne16(v[3]) << 16) | rne16(v[2]);
  d.z = (rne16(v[5]) << 16) | rne16(v[4]);
  d.w = (rne16(v[7]) << 16) | rne16(v[6]);
  wfrag[e * 64 + lane] = d;
}

// ---------------- main: fused feature-gen + MFMA GEMM ----------------
// Each wave: 4 tiles of 16 rows (64 rows), full K=1152, N=32 (two 16-col halves).
__global__ __launch_bounds__(256, 2) void kan_main(
    const float* __restrict__ x,
    const uint4* __restrict__ wfrag,
    const float* __restrict__ bias,
    float* __restrict__ out) {
  const int lane = threadIdx.x & 63;
  const int wave = threadIdx.x >> 6;
  const int m    = lane & 15;  // A row-in-tile; also C/D column (within half)
  const int quad = lane >> 4;  // A channel-octet selector; C/D row group
  const long rowbase = ((long)blockIdx.x * 4 + wave) * 64;

  f32x4v acc[4][2];
#pragma unroll
  for (int tl = 0; tl < 4; ++tl)
#pragma unroll
    for (int hh = 0; hh < 2; ++hh)
#pragma unroll
      for (int rr = 0; rr < 4; ++rr) acc[tl][hh][rr] = 0.f;

  const float* xbase = x + (long)m * 128 + quad * 8;

#pragma unroll
  for (int G = 0; G < 4; ++G) {
    const uint4* wf = wfrag + (size_t)G * 18 * 64 + lane;

    // load this G's channel octet for all 4 row-tiles (x read exactly once total)
    float xc[4][8];
#pragma unroll
    for (int tl = 0; tl < 4; ++tl) {
      const float4* p = reinterpret_cast<const float4*>(
          xbase + (rowbase + tl * 16) * 128 + G * 32);
      float4 a = p[0], b = p[1];
      xc[tl][0] = a.x; xc[tl][1] = a.y; xc[tl][2] = a.z; xc[tl][3] = a.w;
      xc[tl][4] = b.x; xc[tl][5] = b.y; xc[tl][6] = b.z; xc[tl][7] = b.w;
    }

    // t = 0 : silu feature
    bf16x8 b0 = __builtin_bit_cast(bf16x8, wf[0]);
    bf16x8 b1 = __builtin_bit_cast(bf16x8, wf[64]);
#pragma unroll
    for (int tl = 0; tl < 4; ++tl) {
      float sv[8];
#pragma unroll
      for (int j = 0; j < 8; ++j) sv[j] = siluf(xc[tl][j]);
      bf16x8 af = packfrag(sv);
      acc[tl][0] = __builtin_amdgcn_mfma_f32_16x16x32_bf16(af, b0, acc[tl][0], 0, 0, 0);
      acc[tl][1] = __builtin_amdgcn_mfma_f32_16x16x32_bf16(af, b1, acc[tl][1], 0, 0, 0);
    }

    // gaussian recurrence state: p = E0, ratio r ; basis_k ∝ p * r^k (g_k in weights)
    float pg[4][8], rg[4][8];
#pragma unroll
    for (int tl = 0; tl < 4; ++tl)
#pragma unroll
      for (int j = 0; j < 8; ++j) {
        float u = fmaf(xc[tl][j], INVH, NC0H);
        pg[tl][j] = fexp2(A2f * u * u);
        rg[tl][j] = fexp2(B2f * u);
      }

#pragma unroll
    for (int t = 1; t <= 8; ++t) {
      bf16x8 c0 = __builtin_bit_cast(bf16x8, wf[(t * 2) * 64]);
      bf16x8 c1 = __builtin_bit_cast(bf16x8, wf[(t * 2 + 1) * 64]);
#pragma unroll
      for (int tl = 0; tl < 4; ++tl) {
        bf16x8 af = packfrag(pg[tl]);
        acc[tl][0] = __builtin_amdgcn_mfma_f32_16x16x32_bf16(af, c0, acc[tl][0], 0, 0, 0);
        acc[tl][1] = __builtin_amdgcn_mfma_f32_16x16x32_bf16(af, c1, acc[tl][1], 0, 0, 0);
        if (t < 8) {
#pragma unroll
          for (int j = 0; j < 8; ++j) pg[tl][j] *= rg[tl][j];
        }
      }
    }
  }

  // epilogue: C/D layout col = lane&15 (per half), row = quad*4 + reg
  const float bv0 = bias[m];
  const float bv1 = bias[m + 16];
#pragma unroll
  for (int tl = 0; tl < 4; ++tl) {
#pragma unroll
    for (int rr = 0; rr < 4; ++rr) {
      long row = rowbase + tl * 16 + quad * 4 + rr;
      out[row * 32 + m]      = acc[tl][0][rr] + bv0;
      out[row * 32 + m + 16] = acc[tl][1][rr] + bv1;
    }
  }
}

extern "C" void kernel_launch(void* const* d_in, const int* in_sizes, int n_in,
                              void* d_out, int out_size, void* d_ws, size_t ws_size,
                              hipStream_t stream) {
  const float* x     = (const float*)d_in[0]; // (131072,128)
  const float* coeff = (const float*)d_in[1]; // (128,32,8)
  const float* bw    = (const float*)d_in[2]; // (128,32)
  const float* bb    = (const float*)d_in[3]; // (128,32)
  const float* ew    = (const float*)d_in[4]; // (128,32)

  uint4* wfrag = (uint4*)d_ws;                       // 72*64*16 = 73728 B
  float* bias  = (float*)((char*)d_ws + 73728);      // 32 floats

  kan_prep<<<19, 256, 0, stream>>>(coeff, bw, bb, ew, wfrag, bias);
  kan_main<<<512, 256, 0, stream>>>(x, wfrag, bias, (float*)d_out);
}

// Round 2
// 121.707 us; speedup vs baseline: 1.0478x; 1.0478x over previous
//
#include <hip/hip_runtime.h>

typedef short bf16x8 __attribute__((ext_vector_type(8)));   // 8 bf16 in 4 VGPRs
typedef float f32x4v __attribute__((ext_vector_type(4)));

// ---- constants derived from the reference ----
// grid = linspace(-1,1,12); centers c_k = -1 + (3+k)*2/11, k=0..7
// h = 0.4 + 1e-6 ; z_k = (x - c_k)/h = u - k*DLT,  u = (x - c0)/h
// basis_k = exp(-z_k^2/2) = exp2(A2*u^2) * exp2(B2*u)^k * exp2(GCF*k^2)
// exp2(GCF*k^2) is constant per k and folded into the weights at prep time.
constexpr double H_D    = 0.4 + 1e-6;
constexpr double INVH_D = 1.0 / H_D;
constexpr double C0_D   = -1.0 + 6.0 / 11.0;
constexpr double DLT_D  = (2.0 / 11.0) / H_D;
constexpr double L2E_D  = 1.4426950408889634;

constexpr float INVH = (float)INVH_D;
constexpr float NC0H = (float)(-C0_D * INVH_D);           // u = x*INVH + NC0H
constexpr float A2f  = (float)(-0.5 * L2E_D);             // E0 = exp2(A2*u*u)
constexpr float B2f  = (float)(DLT_D * L2E_D);            // r  = exp2(B2*u)
constexpr float GCF  = (float)(-0.5 * DLT_D * DLT_D * L2E_D); // g_k = exp2(GCF*k*k)
constexpr float NL2E = (float)(-L2E_D);

__device__ __forceinline__ float fexp2(float v) {
#if __has_builtin(__builtin_amdgcn_exp2f)
  return __builtin_amdgcn_exp2f(v);
#else
  return exp2f(v);
#endif
}
__device__ __forceinline__ float frcp(float v) {
#if __has_builtin(__builtin_amdgcn_rcpf)
  return __builtin_amdgcn_rcpf(v);
#else
  return 1.0f / v;
#endif
}
__device__ __forceinline__ float siluf(float v) {
  // v * sigmoid(v) = v / (1 + 2^(-log2e * v))
  return v * frcp(1.0f + fexp2(NL2E * v));
}
// pack two fp32 -> one dword of two bf16 (round-half-up), via v_perm_b32
__device__ __forceinline__ unsigned pk2(float lo, float hi) {
  unsigned a = __float_as_uint(hi) + 0x8000u;
  unsigned b = __float_as_uint(lo) + 0x8000u;
  return __builtin_amdgcn_perm(a, b, 0x07060302u); // [a.hi16 : b.hi16]
}
__device__ __forceinline__ bf16x8 packfrag(const float (&v)[8]) {
  uint4 d;
  d.x = pk2(v[0], v[1]);
  d.y = pk2(v[2], v[3]);
  d.z = pk2(v[4], v[5]);
  d.w = pk2(v[6], v[7]);
  return __builtin_bit_cast(bf16x8, d);
}
// RNE fp32 -> bf16 (prep path)
__device__ __forceinline__ unsigned rne16(float f) {
  unsigned u = __float_as_uint(f);
  return (u + 0x7fffu + ((u >> 16) & 1u)) >> 16;
}

// ---------------- prep: build fragment-ordered bf16 weights + bias ----------------
// K ordering: k = G*288 + t*32 + c   (G=0..3 channel-groups of 32, t=0..8 feature,
//                                     c = quad*8 + j channel within group)
// Fragment entry e = (G*9+t)*2 + h  (h = column half), lane l: col n = h*16 + (l&15),
// channels cbase = G*32 + (l>>4)*8 + (0..7)  -> matches MFMA B[k=quad*8+j][n=lane&15].
__global__ void kan_prep(const float* __restrict__ coeff,
                         const float* __restrict__ bw,
                         const float* __restrict__ bb,
                         const float* __restrict__ ew,
                         uint4* __restrict__ wfrag,
                         float* __restrict__ bias) {
  if (blockIdx.x == 18) {
    int n = threadIdx.x;
    if (n < 32) {
      float s = 0.f;
      for (int i = 0; i < 128; ++i) s += ew[i * 32 + n] * bb[i * 32 + n];
      bias[n] = s;
    }
    return;
  }
  const int e    = blockIdx.x * 4 + (threadIdx.x >> 6); // 0..71  (= s*2 + h)
  const int lane = threadIdx.x & 63;
  const int s = e >> 1, h = e & 1;
  const int G = s / 9, t = s % 9;
  const int n = h * 16 + (lane & 15);
  const int cbase = G * 32 + (lane >> 4) * 8;
  float v[8];
  if (t == 0) {
#pragma unroll
    for (int j = 0; j < 8; ++j) {
      int i = cbase + j;
      v[j] = ew[i * 32 + n] * bw[i * 32 + n];
    }
  } else {
    const int k = t - 1;
    const float g = exp2f(GCF * (float)(k * k)); // fold g_k into weight
#pragma unroll
    for (int j = 0; j < 8; ++j) {
      int i = cbase + j;
      v[j] = ew[i * 32 + n] * coeff[(i * 32 + n) * 8 + k] * g;
    }
  }
  uint4 d;
  d.x = (rne16(v[1]) << 16) | rne16(v[0]);
  d.y = (rne16(v[3]) << 16) | rne16(v[2]);
  d.z = (rne16(v[5]) << 16) | rne16(v[4]);
  d.w = (rne16(v[7]) << 16) | rne16(v[6]);
  wfrag[e * 64 + lane] = d;
}

// ---------------- main: fused feature-gen + MFMA GEMM ----------------
// Each wave: 2 tiles of 16 rows (32 rows), full K=1152, N=32 (two 16-col halves).
// x is consumed into compact state (af0 pack + pg/rg) immediately, next-G x
// prefetch issues before the t-loop so HBM latency overlaps the MFMA/VALU body.
__global__ __launch_bounds__(256, 4) void kan_main(
    const float* __restrict__ x,
    const uint4* __restrict__ wfrag,
    const float* __restrict__ bias,
    float* __restrict__ out) {
  const int lane = threadIdx.x & 63;
  const int wave = threadIdx.x >> 6;
  const int m    = lane & 15;  // A row-in-tile; also C/D column (within half)
  const int quad = lane >> 4;  // A channel-octet selector; C/D row group
  const long rowbase = ((long)blockIdx.x * 4 + wave) * 32;

  f32x4v acc[2][2];
#pragma unroll
  for (int tl = 0; tl < 2; ++tl)
#pragma unroll
    for (int hh = 0; hh < 2; ++hh)
#pragma unroll
      for (int rr = 0; rr < 4; ++rr) acc[tl][hh][rr] = 0.f;

  // per-lane x base: row (rowbase + tl*16 + m), octet quad*8, group G*32
  const float* xbase = x + (rowbase + m) * 128 + (long)quad * 8;

  float xb[2][8];
#pragma unroll
  for (int tl = 0; tl < 2; ++tl) {
    const float4* p =
        reinterpret_cast<const float4*>(xbase + (long)tl * 16 * 128);
    float4 a = p[0], b = p[1];
    xb[tl][0] = a.x; xb[tl][1] = a.y; xb[tl][2] = a.z; xb[tl][3] = a.w;
    xb[tl][4] = b.x; xb[tl][5] = b.y; xb[tl][6] = b.z; xb[tl][7] = b.w;
  }

#pragma unroll
  for (int G = 0; G < 4; ++G) {
    const uint4* wf = wfrag + (size_t)G * 18 * 64 + lane;

    // ---- consume xb into compact per-G state ----
    bf16x8 af0[2];
    float pg[2][8], rg[2][8];
#pragma unroll
    for (int tl = 0; tl < 2; ++tl) {
      float sv[8];
#pragma unroll
      for (int j = 0; j < 8; ++j) sv[j] = siluf(xb[tl][j]);
      af0[tl] = packfrag(sv);
#pragma unroll
      for (int j = 0; j < 8; ++j) {
        float u = fmaf(xb[tl][j], INVH, NC0H);
        pg[tl][j] = fexp2(A2f * u * u);
        rg[tl][j] = fexp2(B2f * u);
      }
    }

    // ---- prefetch next G's x; latency overlaps the t-loop below ----
    if (G < 3) {
#pragma unroll
      for (int tl = 0; tl < 2; ++tl) {
        const float4* p = reinterpret_cast<const float4*>(
            xbase + (long)tl * 16 * 128 + (G + 1) * 32);
        float4 a = p[0], b = p[1];
        xb[tl][0] = a.x; xb[tl][1] = a.y; xb[tl][2] = a.z; xb[tl][3] = a.w;
        xb[tl][4] = b.x; xb[tl][5] = b.y; xb[tl][6] = b.z; xb[tl][7] = b.w;
      }
    }

    // ---- t = 0 : silu feature ----
    bf16x8 b0 = __builtin_bit_cast(bf16x8, wf[0]);
    bf16x8 b1 = __builtin_bit_cast(bf16x8, wf[64]);
#pragma unroll
    for (int tl = 0; tl < 2; ++tl) {
      acc[tl][0] = __builtin_amdgcn_mfma_f32_16x16x32_bf16(af0[tl], b0, acc[tl][0], 0, 0, 0);
      acc[tl][1] = __builtin_amdgcn_mfma_f32_16x16x32_bf16(af0[tl], b1, acc[tl][1], 0, 0, 0);
    }

    // ---- t = 1..8 : gaussian recurrence (g_k folded into weights) ----
#pragma unroll
    for (int t = 1; t <= 8; ++t) {
      bf16x8 c0 = __builtin_bit_cast(bf16x8, wf[(t * 2) * 64]);
      bf16x8 c1 = __builtin_bit_cast(bf16x8, wf[(t * 2 + 1) * 64]);
#pragma unroll
      for (int tl = 0; tl < 2; ++tl) {
        bf16x8 af = packfrag(pg[tl]);
        acc[tl][0] = __builtin_amdgcn_mfma_f32_16x16x32_bf16(af, c0, acc[tl][0], 0, 0, 0);
        acc[tl][1] = __builtin_amdgcn_mfma_f32_16x16x32_bf16(af, c1, acc[tl][1], 0, 0, 0);
        if (t < 8) {
#pragma unroll
          for (int j = 0; j < 8; ++j) pg[tl][j] *= rg[tl][j];
        }
      }
    }
  }

  // epilogue: C/D layout col = lane&15 (per half), row = quad*4 + reg
  const float bv0 = bias[m];
  const float bv1 = bias[m + 16];
#pragma unroll
  for (int tl = 0; tl < 2; ++tl) {
#pragma unroll
    for (int rr = 0; rr < 4; ++rr) {
      long row = rowbase + tl * 16 + quad * 4 + rr;
      out[row * 32 + m]      = acc[tl][0][rr] + bv0;
      out[row * 32 + m + 16] = acc[tl][1][rr] + bv1;
    }
  }
}

extern "C" void kernel_launch(void* const* d_in, const int* in_sizes, int n_in,
                              void* d_out, int out_size, void* d_ws, size_t ws_size,
                              hipStream_t stream) {
  const float* x     = (const float*)d_in[0]; // (131072,128)
  const float* coeff = (const float*)d_in[1]; // (128,32,8)
  const float* bw    = (const float*)d_in[2]; // (128,32)
  const float* bb    = (const float*)d_in[3]; // (128,32)
  const float* ew    = (const float*)d_in[4]; // (128,32)

  uint4* wfrag = (uint4*)d_ws;                       // 72*64*16 = 73728 B
  float* bias  = (float*)((char*)d_ws + 73728);      // 32 floats

  kan_prep<<<19, 256, 0, stream>>>(coeff, bw, bb, ew, wfrag, bias);
  kan_main<<<1024, 256, 0, stream>>>(x, wfrag, bias, (float*)d_out);
}